// Round 1
// baseline (243.634 us; speedup 1.0000x reference)
//
#include <hip/hip_runtime.h>

// Problem: B=8,N=64,H=256,nE=256,E=64,HID=512,OUT=1
// out[bn,e] = relu(relu(hp[bn]+ep[e]+b1) @ W2 + b2) @ W3 + b3
// hp = h_all@W1[:256], ep = e_feat@W1[256:]
// Dominant: 131072x512x512 bf16 MFMA GEMM with fused W3 epilogue.

typedef __attribute__((ext_vector_type(8))) short bf16x8;   // 8 bf16 (4 VGPRs)
typedef __attribute__((ext_vector_type(4))) float f32x4;    // MFMA acc

#define LDT 72   // padded LDS row stride in bf16 (144B = 36 words -> bank-uniform)

static __device__ __forceinline__ unsigned short f2bf(float x) {
  unsigned int u = __float_as_uint(x);
  u += 0x7fffu + ((u >> 16) & 1u);   // RNE
  return (unsigned short)(u >> 16);
}

// hpb[bn][k] = sum_h h_all[bn][h]*W1[h][k] + b1[k]   (512x512 f32)
__global__ __launch_bounds__(256) void k_hpart(const float* __restrict__ h_all,
                                               const float* __restrict__ W1,
                                               const float* __restrict__ b1,
                                               float* __restrict__ hpb) {
  __shared__ float hs[4][256];
  const int t = threadIdx.x;
  const int r0 = blockIdx.x * 4;
  #pragma unroll
  for (int i = 0; i < 4; ++i) hs[i][t] = h_all[(r0 + i) * 256 + t];
  __syncthreads();
  float2 acc[4];
  #pragma unroll
  for (int i = 0; i < 4; ++i) acc[i] = make_float2(0.f, 0.f);
  for (int k = 0; k < 256; ++k) {
    float2 wv = *(const float2*)(W1 + (size_t)k * 512 + 2 * t);
    #pragma unroll
    for (int i = 0; i < 4; ++i) {
      acc[i].x = fmaf(hs[i][k], wv.x, acc[i].x);
      acc[i].y = fmaf(hs[i][k], wv.y, acc[i].y);
    }
  }
  float2 bv = *(const float2*)(b1 + 2 * t);
  #pragma unroll
  for (int i = 0; i < 4; ++i) {
    float2 o = make_float2(acc[i].x + bv.x, acc[i].y + bv.y);
    *(float2*)(hpb + (size_t)(r0 + i) * 512 + 2 * t) = o;
  }
}

// ep[e][k] = sum_d e_feat[e][d]*W1[256+d][k]   (256x512 f32, no bias: b1 lives in hpb)
__global__ __launch_bounds__(256) void k_epart(const float* __restrict__ e_feat,
                                               const float* __restrict__ W1,
                                               float* __restrict__ ep) {
  __shared__ float es[4][64];
  const int t = threadIdx.x;
  const int r0 = blockIdx.x * 4;
  es[t >> 6][t & 63] = e_feat[(r0 + (t >> 6)) * 64 + (t & 63)];
  __syncthreads();
  float2 acc[4];
  #pragma unroll
  for (int i = 0; i < 4; ++i) acc[i] = make_float2(0.f, 0.f);
  for (int k = 0; k < 64; ++k) {
    float2 wv = *(const float2*)(W1 + (size_t)(256 + k) * 512 + 2 * t);
    #pragma unroll
    for (int i = 0; i < 4; ++i) {
      acc[i].x = fmaf(es[i][k], wv.x, acc[i].x);
      acc[i].y = fmaf(es[i][k], wv.y, acc[i].y);
    }
  }
  #pragma unroll
  for (int i = 0; i < 4; ++i)
    *(float2*)(ep + (size_t)(r0 + i) * 512 + 2 * t) = acc[i];
}

// w2t[c][k] = bf16(W2[k][c])  (512x512 bf16, col-major of W2 so B-frags read contiguous)
__global__ __launch_bounds__(256) void k_w2t(const float* __restrict__ W2,
                                             unsigned short* __restrict__ w2t) {
  const int c = blockIdx.x;
  const int t = threadIdx.x;
  float a0 = W2[(size_t)(2 * t) * 512 + c];
  float a1 = W2[(size_t)(2 * t + 1) * 512 + c];
  ushort2 o;
  o.x = f2bf(a0);
  o.y = f2bf(a1);
  *(ushort2*)(w2t + (size_t)c * 512 + 2 * t) = o;
}

// Main fused kernel: 1024 blocks, each = (bn, e-half of 128 rows).
// 128x128 N-tiles x4, BK=64, wave tile 64x64 (4x4 frags of 16x16x32 bf16).
__global__ __launch_bounds__(256, 2) void k_main(
    const float* __restrict__ hpb, const float* __restrict__ ep,
    const unsigned short* __restrict__ w2t, const float* __restrict__ b2,
    const float* __restrict__ W3, const float* __restrict__ b3,
    float* __restrict__ out) {
  __shared__ unsigned short x1s[128 * LDT];   // 18432 B
  __shared__ unsigned short w2s[128 * LDT];   // 18432 B
  __shared__ float osum_lds[2][128];          // 1024 B

  const int t = threadIdx.x;
  const int lane = t & 63;
  const int w = t >> 6;        // wave 0..3
  const int wr = w >> 1;       // row half (64 rows)
  const int wc = w & 1;        // col half (64 cols)
  const int l15 = lane & 15;   // frag col (B/C) / row (A)
  const int l4 = lane >> 4;    // k-group / row quad
  const int bn = blockIdx.x >> 1;
  const int e0 = (blockIdx.x & 1) << 7;

  const float* hprow = hpb + (size_t)bn * 512;

  // staging index helpers
  const int sk4 = t & 15;   // float4 slot within 64-k chunk (16 slots)
  const int sr = t >> 4;    // base row 0..15 (x8 passes)
  const int wkq = t & 7;    // 16B slot within 64-k row (8 slots)
  const int wcb = t >> 3;   // base col 0..31 (x4 passes)

  float osum[16];
  #pragma unroll
  for (int i = 0; i < 16; ++i) osum[i] = 0.f;

  #pragma unroll 1
  for (int nt = 0; nt < 4; ++nt) {
    f32x4 acc[4][4] = {};

    #pragma unroll 1
    for (int kc = 0; kc < 8; ++kc) {
      __syncthreads();   // previous chunk's frag reads complete before overwrite
      // --- stage x1 chunk: 128 rows x 64 k, relu(ep + hpb) -> bf16
      {
        const int kg = kc * 64 + sk4 * 4;
        const float4 hp4 = *(const float4*)(hprow + kg);
        #pragma unroll
        for (int rr = 0; rr < 8; ++rr) {
          const int r = sr + rr * 16;
          float4 ev = *(const float4*)(ep + (size_t)(e0 + r) * 512 + kg);
          ushort4 pk;
          pk.x = f2bf(fmaxf(ev.x + hp4.x, 0.f));
          pk.y = f2bf(fmaxf(ev.y + hp4.y, 0.f));
          pk.z = f2bf(fmaxf(ev.z + hp4.z, 0.f));
          pk.w = f2bf(fmaxf(ev.w + hp4.w, 0.f));
          *(ushort4*)(&x1s[r * LDT + sk4 * 4]) = pk;
        }
      }
      // --- stage W2 chunk: 128 cols x 64 k (bf16 copy from w2t[col][k])
      {
        const unsigned short* src = w2t + (size_t)(nt * 128) * 512 + kc * 64;
        #pragma unroll
        for (int cc = 0; cc < 4; ++cc) {
          const int c = wcb + cc * 32;
          uint4 v = *(const uint4*)(src + (size_t)c * 512 + wkq * 8);
          *(uint4*)(&w2s[c * LDT + wkq * 8]) = v;
        }
      }
      __syncthreads();
      // --- MFMA: 2 k-steps of 32, 16 MFMAs each
      #pragma unroll
      for (int ks = 0; ks < 2; ++ks) {
        bf16x8 a[4], b[4];
        #pragma unroll
        for (int i = 0; i < 4; ++i)
          a[i] = *(const bf16x8*)(&x1s[(wr * 64 + i * 16 + l15) * LDT + ks * 32 + l4 * 8]);
        #pragma unroll
        for (int j = 0; j < 4; ++j)
          b[j] = *(const bf16x8*)(&w2s[(wc * 64 + j * 16 + l15) * LDT + ks * 32 + l4 * 8]);
        #pragma unroll
        for (int i = 0; i < 4; ++i)
          #pragma unroll
          for (int j = 0; j < 4; ++j)
            acc[i][j] = __builtin_amdgcn_mfma_f32_16x16x32_bf16(a[i], b[j], acc[i][j], 0, 0, 0);
      }
    }
    // --- fused epilogue for this N-tile: osum[row] += relu(acc + b2[col]) * W3[col]
    #pragma unroll
    for (int j = 0; j < 4; ++j) {
      const int col = nt * 128 + wc * 64 + j * 16 + l15;
      const float b2v = b2[col];
      const float w3v = W3[col];
      #pragma unroll
      for (int i = 0; i < 4; ++i)
        #pragma unroll
        for (int r = 0; r < 4; ++r) {
          float y = fmaxf(acc[i][j][r] + b2v, 0.f);   // C/D: col=l&15, row=(l>>4)*4+r
          osum[i * 4 + r] = fmaf(y, w3v, osum[i * 4 + r]);
        }
    }
  }

  // reduce over the 16 col-lanes (rows are shared by lanes differing in l15)
  #pragma unroll
  for (int i = 0; i < 16; ++i) {
    float v = osum[i];
    v += __shfl_xor(v, 1);
    v += __shfl_xor(v, 2);
    v += __shfl_xor(v, 4);
    v += __shfl_xor(v, 8);
    osum[i] = v;
  }
  if (l15 == 0) {
    #pragma unroll
    for (int i = 0; i < 4; ++i)
      #pragma unroll
      for (int r = 0; r < 4; ++r)
        osum_lds[wc][wr * 64 + i * 16 + l4 * 4 + r] = osum[i * 4 + r];
  }
  __syncthreads();
  if (t < 128) {
    out[(size_t)bn * 256 + e0 + t] = osum_lds[0][t] + osum_lds[1][t] + b3[0];
  }
}

extern "C" void kernel_launch(void* const* d_in, const int* in_sizes, int n_in,
                              void* d_out, int out_size, void* d_ws, size_t ws_size,
                              hipStream_t stream) {
  const float* h_all  = (const float*)d_in[0];   // (8,64,256)
  const float* e_feat = (const float*)d_in[1];   // (256,64)
  const float* W1     = (const float*)d_in[2];   // (320,512)
  const float* b1     = (const float*)d_in[3];   // (512,)
  const float* W2     = (const float*)d_in[4];   // (512,512)
  const float* b2     = (const float*)d_in[5];   // (512,)
  const float* W3     = (const float*)d_in[6];   // (512,1)
  const float* b3     = (const float*)d_in[7];   // (1,)
  float* out = (float*)d_out;                    // 131072 f32

  // workspace: hpb 1MB | ep 512KB | w2t 512KB  (total 2MB)
  float* hpb = (float*)d_ws;
  float* ep = hpb + 512 * 512;
  unsigned short* w2t = (unsigned short*)(ep + 256 * 512);

  hipLaunchKernelGGL(k_hpart, dim3(128), dim3(256), 0, stream, h_all, W1, b1, hpb);
  hipLaunchKernelGGL(k_epart, dim3(64), dim3(256), 0, stream, e_feat, W1, ep);
  hipLaunchKernelGGL(k_w2t, dim3(512), dim3(256), 0, stream, W2, w2t);
  hipLaunchKernelGGL(k_main, dim3(1024), dim3(256), 0, stream, hpb, ep, w2t, b2, W3, b3, out);
}

// Round 2
// 154.236 us; speedup vs baseline: 1.5796x; 1.5796x over previous
//
#include <hip/hip_runtime.h>
#include <hip/hip_bf16.h>

// out[bn,e] = relu(relu(hp[bn]+ep[e]+b1) @ W2 + b2) @ W3 + b3
// hp = h_all@W1[:256], ep = e_feat@W1[256:]
// R2: barrier-free K-loop. x1 (64 rows x 512 k bf16) staged ONCE per block in
// swizzled LDS; W2 pre-packed in B-frag order -> direct global->reg loads.

typedef __attribute__((ext_vector_type(8))) short bf16x8;   // 8 bf16
typedef __attribute__((ext_vector_type(4))) float f32x4;    // MFMA acc

static __device__ __forceinline__ ushort2 pk_bf16(float a, float b) {
  union { __hip_bfloat162 h; ushort2 u; } c;
  c.h = __float22bfloat162_rn(make_float2(a, b));
  return c.u;
}

// ---------------- fused prep ----------------
// blocks 0..63   : hpb rows (8/blk)  hpb[r][k] = sum_h h[r][h]*W1[h][k] + b1[k]
// blocks 64..95  : ep rows  (8/blk)  ep[e][k]  = sum_d e[e][d]*W1[256+d][k]
// blocks 96..159 : w2f pack (64x64 W2 tile -> bf16 B-frag records)
//   record(jg,ks): lane l holds W2[k = ks*32+(l>>4)*8 + u][col = jg*16+(l&15)], u=0..7
__global__ __launch_bounds__(256) void k_prep(
    const float* __restrict__ h_all, const float* __restrict__ e_feat,
    const float* __restrict__ W1, const float* __restrict__ b1,
    const float* __restrict__ W2,
    float* __restrict__ hpb, float* __restrict__ ep,
    unsigned short* __restrict__ w2f) {
  __shared__ float sm[64 * 68];   // 17408 B, reused per role
  const int t = threadIdx.x;
  const int b = blockIdx.x;

  if (b < 64) {                       // ---- hp part
    const int r0 = b * 8;
    float (*hs)[256] = (float(*)[256])sm;
    #pragma unroll
    for (int i = 0; i < 8; ++i) hs[i][t] = h_all[(size_t)(r0 + i) * 256 + t];
    __syncthreads();
    float2 acc[8];
    #pragma unroll
    for (int i = 0; i < 8; ++i) acc[i] = make_float2(0.f, 0.f);
    for (int k = 0; k < 256; ++k) {
      float2 wv = *(const float2*)(W1 + (size_t)k * 512 + 2 * t);
      #pragma unroll
      for (int i = 0; i < 8; ++i) {
        acc[i].x = fmaf(hs[i][k], wv.x, acc[i].x);
        acc[i].y = fmaf(hs[i][k], wv.y, acc[i].y);
      }
    }
    float2 bv = *(const float2*)(b1 + 2 * t);
    #pragma unroll
    for (int i = 0; i < 8; ++i) {
      float2 o = make_float2(acc[i].x + bv.x, acc[i].y + bv.y);
      *(float2*)(hpb + (size_t)(r0 + i) * 512 + 2 * t) = o;
    }
  } else if (b < 96) {                // ---- ep part
    const int r0 = (b - 64) * 8;
    sm[t] = e_feat[(size_t)r0 * 64 + t];
    sm[256 + t] = e_feat[(size_t)r0 * 64 + 256 + t];
    __syncthreads();
    float2 acc[8];
    #pragma unroll
    for (int i = 0; i < 8; ++i) acc[i] = make_float2(0.f, 0.f);
    for (int k = 0; k < 64; ++k) {
      float2 wv = *(const float2*)(W1 + (size_t)(256 + k) * 512 + 2 * t);
      #pragma unroll
      for (int i = 0; i < 8; ++i) {
        acc[i].x = fmaf(sm[i * 64 + k], wv.x, acc[i].x);
        acc[i].y = fmaf(sm[i * 64 + k], wv.y, acc[i].y);
      }
    }
    #pragma unroll
    for (int i = 0; i < 8; ++i)
      *(float2*)(ep + (size_t)(r0 + i) * 512 + 2 * t) =
          make_float2(acc[i].x, acc[i].y);
  } else {                            // ---- w2f pack
    const int bb = b - 96;            // 0..63
    const int k0 = (bb >> 3) * 64;
    const int c0 = (bb & 7) * 64;
    // load 64x64 f32 tile of W2 (coalesced), stride 68 in LDS
    #pragma unroll
    for (int rr = 0; rr < 4; ++rr) {
      const int row = rr * 16 + (t >> 4);
      float4 v = *(const float4*)(W2 + (size_t)(k0 + row) * 512 + c0 + (t & 15) * 4);
      *(float4*)(&sm[row * 68 + (t & 15) * 4]) = v;
    }
    __syncthreads();
    #pragma unroll
    for (int s2 = 0; s2 < 2; ++s2) {
      const int s = t * 2 + s2;       // 0..511 (8 records x 64 lanes)
      const int rec = s >> 6, l = s & 63;
      const int jg = (c0 >> 4) + (rec & 3);
      const int ksg = (k0 >> 5) + (rec >> 2);
      const int cl = (rec & 3) * 16 + (l & 15);
      const int kl = (rec >> 2) * 32 + (l >> 4) * 8;
      union { ushort2 o[4]; uint4 v; } u;
      #pragma unroll
      for (int uu = 0; uu < 4; ++uu)
        u.o[uu] = pk_bf16(sm[(kl + 2 * uu) * 68 + cl], sm[(kl + 2 * uu + 1) * 68 + cl]);
      *(uint4*)(w2f + ((size_t)(jg * 16 + ksg) * 64 + l) * 8) = u.v;
    }
  }
}

// ---------------- main fused kernel ----------------
// 2048 blocks x 256 thr. Block = 64 rows (bn, e-quarter) x all 512 cols.
// Wave w: cols w*128..+128 (j=0..7), rows 0..63 (i=0..3).
__global__ __launch_bounds__(256, 2) void k_main(
    const float* __restrict__ hpb, const float* __restrict__ ep,
    const unsigned short* __restrict__ w2f, const float* __restrict__ b2,
    const float* __restrict__ W3, const float* __restrict__ b3,
    float* __restrict__ out) {
  __shared__ unsigned short x1s[64 * 512];   // 64 KiB, XOR-swizzled 16B chunks

  const int t = threadIdx.x;
  const int lane = t & 63;
  const int w = t >> 6;
  const int l15 = lane & 15, l4 = lane >> 4;
  const int bn = blockIdx.x >> 2;
  const int e0 = (blockIdx.x & 3) << 6;
  const float* hprow = hpb + (size_t)bn * 512;

  // ---- stage x1 once: relu(hp + ep) -> bf16, chunk' = chunk ^ (row&7)
  {
    const int kk = (t & 127) * 4;      // k offset, fixed per thread
    const int rbase = t >> 7;          // 0/1
    const int ch = kk >> 3;            // 16B-chunk index 0..63
    const int kin = kk & 7;            // 0 or 4 (ushort within chunk)
    const float4 hv = *(const float4*)(hprow + kk);
    #pragma unroll 4
    for (int rr = 0; rr < 32; ++rr) {
      const int r = rr * 2 + rbase;
      float4 ev = *(const float4*)(ep + (size_t)(e0 + r) * 512 + kk);
      ushort2 p0 = pk_bf16(fmaxf(ev.x + hv.x, 0.f), fmaxf(ev.y + hv.y, 0.f));
      ushort2 p1 = pk_bf16(fmaxf(ev.z + hv.z, 0.f), fmaxf(ev.w + hv.w, 0.f));
      ushort4 pk4 = {p0.x, p0.y, p1.x, p1.y};
      *(ushort4*)(&x1s[r * 512 + (ch ^ (r & 7)) * 8 + kin]) = pk4;
    }
  }

  // b-frag stream base: record (jg = w*8+j, ks), lane slot of 8 bf16
  const unsigned short* wrec = w2f + (size_t)w * 65536 + (size_t)lane * 8;
  bf16x8 bcur[8], bnxt[8];
  #pragma unroll
  for (int j = 0; j < 8; ++j)
    bcur[j] = *(const bf16x8*)(wrec + j * 8192);   // ks=0, in flight over barrier
  __syncthreads();

  f32x4 acc[4][8] = {};
  #pragma unroll 2
  for (int ks = 0; ks < 16; ++ks) {
    const int ksn = (ks + 1) & 15;     // wraps at end (dummy reload, no OOB)
    const int chp = (((ks * 4 + l4) ^ (l15 & 7)) * 8);
    bf16x8 a[4];
    #pragma unroll
    for (int i = 0; i < 4; ++i)
      a[i] = *(const bf16x8*)(&x1s[(i * 16 + l15) * 512 + chp]);
    #pragma unroll
    for (int j = 0; j < 8; ++j)
      bnxt[j] = *(const bf16x8*)(wrec + j * 8192 + ksn * 512);
    #pragma unroll
    for (int i = 0; i < 4; ++i)
      #pragma unroll
      for (int j = 0; j < 8; ++j)
        acc[i][j] = __builtin_amdgcn_mfma_f32_16x16x32_bf16(a[i], bcur[j], acc[i][j], 0, 0, 0);
    #pragma unroll
    for (int j = 0; j < 8; ++j) bcur[j] = bnxt[j];
  }

  // ---- fused epilogue: osum[row] = sum_n relu(acc + b2[n]) * W3[n]
  float part[16];
  #pragma unroll
  for (int u = 0; u < 16; ++u) part[u] = 0.f;
  #pragma unroll
  for (int j = 0; j < 8; ++j) {
    const int n = w * 128 + j * 16 + l15;
    const float b2v = b2[n], w3v = W3[n];
    #pragma unroll
    for (int i = 0; i < 4; ++i)
      #pragma unroll
      for (int r = 0; r < 4; ++r)
        part[i * 4 + r] = fmaf(fmaxf(acc[i][j][r] + b2v, 0.f), w3v, part[i * 4 + r]);
  }
  #pragma unroll
  for (int u = 0; u < 16; ++u) {     // reduce over the 16 col-lanes (l15)
    float v = part[u];
    v += __shfl_xor(v, 1);
    v += __shfl_xor(v, 2);
    v += __shfl_xor(v, 4);
    v += __shfl_xor(v, 8);
    part[u] = v;
  }
  __syncthreads();                   // all x1s reads done before aliasing
  float* osum = (float*)x1s;         // [4 waves][64 rows]
  if (l15 == 0) {
    #pragma unroll
    for (int i = 0; i < 4; ++i)
      #pragma unroll
      for (int r = 0; r < 4; ++r)
        osum[w * 64 + i * 16 + l4 * 4 + r] = part[i * 4 + r];
  }
  __syncthreads();
  if (t < 64) {
    float s = b3[0] + osum[t] + osum[64 + t] + osum[128 + t] + osum[192 + t];
    out[(size_t)blockIdx.x * 64 + t] = s;
  }
}

extern "C" void kernel_launch(void* const* d_in, const int* in_sizes, int n_in,
                              void* d_out, int out_size, void* d_ws, size_t ws_size,
                              hipStream_t stream) {
  const float* h_all  = (const float*)d_in[0];   // (8,64,256)
  const float* e_feat = (const float*)d_in[1];   // (256,64)
  const float* W1     = (const float*)d_in[2];   // (320,512)
  const float* b1     = (const float*)d_in[3];   // (512,)
  const float* W2     = (const float*)d_in[4];   // (512,512)
  const float* b2     = (const float*)d_in[5];   // (512,)
  const float* W3     = (const float*)d_in[6];   // (512,1)
  const float* b3     = (const float*)d_in[7];   // (1,)
  float* out = (float*)d_out;                    // 131072 f32

  // workspace: hpb 1MB | ep 512KB | w2f 512KB
  float* hpb = (float*)d_ws;
  float* ep = hpb + 512 * 512;
  unsigned short* w2f = (unsigned short*)(ep + 256 * 512);

  hipLaunchKernelGGL(k_prep, dim3(160), dim3(256), 0, stream,
                     h_all, e_feat, W1, b1, W2, hpb, ep, w2f);
  hipLaunchKernelGGL(k_main, dim3(2048), dim3(256), 0, stream,
                     hpb, ep, w2f, b2, W3, b3, out);
}

// Round 3
// 152.916 us; speedup vs baseline: 1.5933x; 1.0086x over previous
//
#include <hip/hip_runtime.h>
#include <hip/hip_bf16.h>

// out[bn,e] = relu(relu(hp[bn]+ep[e]+b1) @ W2 + b2) @ W3 + b3
// R3: 128-row blocks (512 thr) halve w2f L2 traffic; row-paired waves share
// b-frag streams (L1 dedupe); ep stored bf16; faster prep.

typedef __attribute__((ext_vector_type(8))) short bf16x8;   // 8 bf16
typedef __attribute__((ext_vector_type(4))) float f32x4;    // MFMA acc

static __device__ __forceinline__ ushort2 pk_bf16(float a, float b) {
  union { __hip_bfloat162 h; ushort2 u; } c;
  c.h = __float22bfloat162_rn(make_float2(a, b));
  return c.u;
}
static __device__ __forceinline__ float bf2f(unsigned short u) {
  union { unsigned int i; float f; } c;
  c.i = ((unsigned int)u) << 16;
  return c.f;
}

// ---------------- fused prep (352 blocks x 256 thr) ----------------
// blocks 0..255  : hpb rows (2/blk)  hpb[r][k] = sum_h h[r][h]*W1[h][k] + b1[k]  (f32)
// blocks 256..287: epb rows (8/blk)  epb[e][k] = bf16(sum_d e[e][d]*W1[256+d][k])
// blocks 288..351: w2f pack (64x64 W2 tile -> bf16 B-frag records)
//   record(jg,ks): lane l holds W2[k = ks*32+(l>>4)*8 + u][col = jg*16+(l&15)], u=0..7
__global__ __launch_bounds__(256) void k_prep(
    const float* __restrict__ h_all, const float* __restrict__ e_feat,
    const float* __restrict__ W1, const float* __restrict__ b1,
    const float* __restrict__ W2,
    float* __restrict__ hpb, unsigned short* __restrict__ epb,
    unsigned short* __restrict__ w2f) {
  __shared__ float sm[64 * 68];   // 17408 B, reused per role
  const int t = threadIdx.x;
  const int b = blockIdx.x;

  if (b < 256) {                      // ---- hp part: 2 rows
    const int r0 = b * 2;
    float (*hs)[256] = (float(*)[256])sm;
    hs[0][t] = h_all[(size_t)r0 * 256 + t];
    hs[1][t] = h_all[(size_t)(r0 + 1) * 256 + t];
    __syncthreads();
    float2 a0 = make_float2(0.f, 0.f), a1 = make_float2(0.f, 0.f);
    #pragma unroll 2
    for (int k = 0; k < 256; k += 4) {
      float2 w0 = *(const float2*)(W1 + (size_t)k * 512 + 2 * t);
      float2 w1 = *(const float2*)(W1 + (size_t)(k + 1) * 512 + 2 * t);
      float2 w2v = *(const float2*)(W1 + (size_t)(k + 2) * 512 + 2 * t);
      float2 w3v = *(const float2*)(W1 + (size_t)(k + 3) * 512 + 2 * t);
      float h00 = hs[0][k], h01 = hs[0][k + 1], h02 = hs[0][k + 2], h03 = hs[0][k + 3];
      float h10 = hs[1][k], h11 = hs[1][k + 1], h12 = hs[1][k + 2], h13 = hs[1][k + 3];
      a0.x = fmaf(h00, w0.x, a0.x); a0.y = fmaf(h00, w0.y, a0.y);
      a1.x = fmaf(h10, w0.x, a1.x); a1.y = fmaf(h10, w0.y, a1.y);
      a0.x = fmaf(h01, w1.x, a0.x); a0.y = fmaf(h01, w1.y, a0.y);
      a1.x = fmaf(h11, w1.x, a1.x); a1.y = fmaf(h11, w1.y, a1.y);
      a0.x = fmaf(h02, w2v.x, a0.x); a0.y = fmaf(h02, w2v.y, a0.y);
      a1.x = fmaf(h12, w2v.x, a1.x); a1.y = fmaf(h12, w2v.y, a1.y);
      a0.x = fmaf(h03, w3v.x, a0.x); a0.y = fmaf(h03, w3v.y, a0.y);
      a1.x = fmaf(h13, w3v.x, a1.x); a1.y = fmaf(h13, w3v.y, a1.y);
    }
    float2 bv = *(const float2*)(b1 + 2 * t);
    *(float2*)(hpb + (size_t)r0 * 512 + 2 * t) = make_float2(a0.x + bv.x, a0.y + bv.y);
    *(float2*)(hpb + (size_t)(r0 + 1) * 512 + 2 * t) = make_float2(a1.x + bv.x, a1.y + bv.y);
  } else if (b < 288) {               // ---- ep part: 8 rows, bf16 out
    const int r0 = (b - 256) * 8;
    sm[t] = e_feat[(size_t)r0 * 64 + t];
    sm[256 + t] = e_feat[(size_t)r0 * 64 + 256 + t];
    __syncthreads();
    float2 acc[8];
    #pragma unroll
    for (int i = 0; i < 8; ++i) acc[i] = make_float2(0.f, 0.f);
    for (int k = 0; k < 64; ++k) {
      float2 wv = *(const float2*)(W1 + (size_t)(256 + k) * 512 + 2 * t);
      #pragma unroll
      for (int i = 0; i < 8; ++i) {
        acc[i].x = fmaf(sm[i * 64 + k], wv.x, acc[i].x);
        acc[i].y = fmaf(sm[i * 64 + k], wv.y, acc[i].y);
      }
    }
    #pragma unroll
    for (int i = 0; i < 8; ++i)
      *(ushort2*)(epb + (size_t)(r0 + i) * 512 + 2 * t) = pk_bf16(acc[i].x, acc[i].y);
  } else {                            // ---- w2f pack
    const int bb = b - 288;           // 0..63
    const int k0 = (bb >> 3) * 64;
    const int c0 = (bb & 7) * 64;
    #pragma unroll
    for (int rr = 0; rr < 4; ++rr) {
      const int row = rr * 16 + (t >> 4);
      float4 v = *(const float4*)(W2 + (size_t)(k0 + row) * 512 + c0 + (t & 15) * 4);
      *(float4*)(&sm[row * 68 + (t & 15) * 4]) = v;
    }
    __syncthreads();
    #pragma unroll
    for (int s2 = 0; s2 < 2; ++s2) {
      const int s = t * 2 + s2;       // 0..511 (8 records x 64 lanes)
      const int rec = s >> 6, l = s & 63;
      const int jg = (c0 >> 4) + (rec & 3);
      const int ksg = (k0 >> 5) + (rec >> 2);
      const int cl = (rec & 3) * 16 + (l & 15);
      const int kl = (rec >> 2) * 32 + (l >> 4) * 8;
      union { ushort2 o[4]; uint4 v; } u;
      #pragma unroll
      for (int uu = 0; uu < 4; ++uu)
        u.o[uu] = pk_bf16(sm[(kl + 2 * uu) * 68 + cl], sm[(kl + 2 * uu + 1) * 68 + cl]);
      *(uint4*)(w2f + ((size_t)(jg * 16 + ksg) * 64 + l) * 8) = u.v;
    }
  }
}

// ---------------- main fused kernel ----------------
// 1024 blocks x 512 thr. Block = 128 rows (one bn, e-half) x all 512 cols.
// Wave w: wc=w&3 -> cols wc*128..+128, wrh=w>>2 -> rows wrh*64..+64.
// Row-paired waves (w, w+4) read identical b-frag streams -> L1 reuse.
__global__ __launch_bounds__(512, 2) void k_main(
    const float* __restrict__ hpb, const unsigned short* __restrict__ epb,
    const unsigned short* __restrict__ w2f, const float* __restrict__ b2,
    const float* __restrict__ W3, const float* __restrict__ b3,
    float* __restrict__ out) {
  __shared__ unsigned short x1s[128 * 512];   // 128 KiB, XOR-swizzled 16B chunks

  const int t = threadIdx.x;
  const int lane = t & 63;
  const int w = t >> 6;          // 0..7
  const int wc = w & 3;          // col group (128 cols)
  const int wrh = w >> 2;        // row half (64 rows)
  const int l15 = lane & 15, l4 = lane >> 4;
  const int bn = blockIdx.x >> 1;
  const int e0 = (blockIdx.x & 1) << 7;
  const float* hprow = hpb + (size_t)bn * 512;

  // b-frag prefetch for ks=0 (in flight across the staging barrier)
  const unsigned short* wrec = w2f + (size_t)wc * 65536 + (size_t)lane * 8;
  bf16x8 bcur[8], bnxt[8];
  #pragma unroll
  for (int j = 0; j < 8; ++j)
    bcur[j] = *(const bf16x8*)(wrec + j * 8192);

  // ---- stage x1 once: relu(hp + ep) -> bf16, chunk' = chunk ^ (row&7)
  {
    const int kk = (t & 127) * 4;   // k offset (4 bf16 per thread)
    const int rbase = t >> 7;       // 0..3
    const int ch = kk >> 3;         // 16B-chunk index 0..63
    const int kin = kk & 7;         // 0 or 4
    const float4 hv = *(const float4*)(hprow + kk);
    #pragma unroll 4
    for (int rr = 0; rr < 32; ++rr) {
      const int r = rr * 4 + rbase;
      ushort4 ev = *(const ushort4*)(epb + (size_t)(e0 + r) * 512 + kk);
      ushort2 p0 = pk_bf16(fmaxf(bf2f(ev.x) + hv.x, 0.f), fmaxf(bf2f(ev.y) + hv.y, 0.f));
      ushort2 p1 = pk_bf16(fmaxf(bf2f(ev.z) + hv.z, 0.f), fmaxf(bf2f(ev.w) + hv.w, 0.f));
      ushort4 pk4 = {p0.x, p0.y, p1.x, p1.y};
      *(ushort4*)(&x1s[r * 512 + (ch ^ (r & 7)) * 8 + kin]) = pk4;
    }
  }
  __syncthreads();

  f32x4 acc[4][8] = {};
  #pragma unroll 2
  for (int ks = 0; ks < 16; ++ks) {
    const int ksn = (ks + 1) & 15;   // wraps at end (dummy reload, no OOB)
    bf16x8 a[4];
    #pragma unroll
    for (int i = 0; i < 4; ++i) {
      const int r = wrh * 64 + i * 16 + l15;        // r&7 == l15&7
      const int chp = (((ks * 4 + l4) ^ (l15 & 7)) * 8);
      a[i] = *(const bf16x8*)(&x1s[r * 512 + chp]);
    }
    #pragma unroll
    for (int j = 0; j < 8; ++j)
      bnxt[j] = *(const bf16x8*)(wrec + j * 8192 + ksn * 512);
    #pragma unroll
    for (int i = 0; i < 4; ++i)
      #pragma unroll
      for (int j = 0; j < 8; ++j)
        acc[i][j] = __builtin_amdgcn_mfma_f32_16x16x32_bf16(a[i], bcur[j], acc[i][j], 0, 0, 0);
    #pragma unroll
    for (int j = 0; j < 8; ++j) bcur[j] = bnxt[j];
  }

  // ---- fused epilogue: osum[row] = sum_n relu(acc + b2[n]) * W3[n]
  float part[16];
  #pragma unroll
  for (int u = 0; u < 16; ++u) part[u] = 0.f;
  #pragma unroll
  for (int j = 0; j < 8; ++j) {
    const int n = wc * 128 + j * 16 + l15;
    const float b2v = b2[n], w3v = W3[n];
    #pragma unroll
    for (int i = 0; i < 4; ++i)
      #pragma unroll
      for (int r = 0; r < 4; ++r)
        part[i * 4 + r] = fmaf(fmaxf(acc[i][j][r] + b2v, 0.f), w3v, part[i * 4 + r]);
  }
  #pragma unroll
  for (int u = 0; u < 16; ++u) {     // reduce over the 16 col-lanes (l15)
    float v = part[u];
    v += __shfl_xor(v, 1);
    v += __shfl_xor(v, 2);
    v += __shfl_xor(v, 4);
    v += __shfl_xor(v, 8);
    part[u] = v;
  }
  __syncthreads();                   // all x1s reads done before aliasing
  float* osum = (float*)x1s;         // [4 col-groups][128 rows]
  if (l15 == 0) {
    #pragma unroll
    for (int i = 0; i < 4; ++i)
      #pragma unroll
      for (int r = 0; r < 4; ++r)
        osum[wc * 128 + wrh * 64 + i * 16 + l4 * 4 + r] = part[i * 4 + r];
  }
  __syncthreads();
  if (t < 128) {
    float s = b3[0] + osum[t] + osum[128 + t] + osum[256 + t] + osum[384 + t];
    out[(size_t)bn * 256 + e0 + t] = s;
  }
}

extern "C" void kernel_launch(void* const* d_in, const int* in_sizes, int n_in,
                              void* d_out, int out_size, void* d_ws, size_t ws_size,
                              hipStream_t stream) {
  const float* h_all  = (const float*)d_in[0];   // (8,64,256)
  const float* e_feat = (const float*)d_in[1];   // (256,64)
  const float* W1     = (const float*)d_in[2];   // (320,512)
  const float* b1     = (const float*)d_in[3];   // (512,)
  const float* W2     = (const float*)d_in[4];   // (512,512)
  const float* b2     = (const float*)d_in[5];   // (512,)
  const float* W3     = (const float*)d_in[6];   // (512,1)
  const float* b3     = (const float*)d_in[7];   // (1,)
  float* out = (float*)d_out;                    // 131072 f32

  // workspace: hpb 1MB f32 | epb 256KB bf16 | w2f 512KB bf16
  float* hpb = (float*)d_ws;
  unsigned short* epb = (unsigned short*)(hpb + 512 * 512);
  unsigned short* w2f = epb + 256 * 512;

  hipLaunchKernelGGL(k_prep, dim3(352), dim3(256), 0, stream,
                     h_all, e_feat, W1, b1, W2, hpb, epb, w2f);
  hipLaunchKernelGGL(k_main, dim3(1024), dim3(512), 0, stream,
                     hpb, epb, w2f, b2, W3, b3, out);
}

// Round 4
// 145.080 us; speedup vs baseline: 1.6793x; 1.0540x over previous
//
#include <hip/hip_runtime.h>
#include <hip/hip_bf16.h>

// out[bn,e] = relu(relu(hp[bn]+ep[e]+b1) @ W2 + b2) @ W3 + b3
// R4: R2 topology (64-row blocks, 256 thr, 2 blocks/CU) + depth-2 B prefetch
// ping-pong + per-block K-offset stagger (spread L2 contention) + bf16 hpb.

typedef __attribute__((ext_vector_type(8))) short bf16x8;   // 8 bf16
typedef __attribute__((ext_vector_type(4))) float f32x4;    // MFMA acc

static __device__ __forceinline__ ushort2 pk_bf16(float a, float b) {
  union { __hip_bfloat162 h; ushort2 u; } c;
  c.h = __float22bfloat162_rn(make_float2(a, b));
  return c.u;
}
static __device__ __forceinline__ float bf2f(unsigned short u) {
  union { unsigned int i; float f; } c;
  c.i = ((unsigned int)u) << 16;
  return c.f;
}

// ---------------- fused prep (352 blocks x 256 thr) ----------------
// blocks 0..255  : hpb rows (2/blk)  hpb[r][k] = bf16(sum_h h[r][h]*W1[h][k] + b1[k])
// blocks 256..287: epb rows (8/blk)  epb[e][k] = bf16(sum_d e[e][d]*W1[256+d][k])
// blocks 288..351: w2f pack (64x64 W2 tile -> bf16 B-frag records)
//   record(jg,ks): lane l holds W2[k = ks*32+(l>>4)*8 + u][col = jg*16+(l&15)], u=0..7
__global__ __launch_bounds__(256) void k_prep(
    const float* __restrict__ h_all, const float* __restrict__ e_feat,
    const float* __restrict__ W1, const float* __restrict__ b1,
    const float* __restrict__ W2,
    unsigned short* __restrict__ hpb, unsigned short* __restrict__ epb,
    unsigned short* __restrict__ w2f) {
  __shared__ float sm[64 * 68];   // 17408 B, reused per role
  const int t = threadIdx.x;
  const int b = blockIdx.x;

  if (b < 256) {                      // ---- hp part: 2 rows, bf16 out
    const int r0 = b * 2;
    float (*hs)[256] = (float(*)[256])sm;
    hs[0][t] = h_all[(size_t)r0 * 256 + t];
    hs[1][t] = h_all[(size_t)(r0 + 1) * 256 + t];
    __syncthreads();
    float2 a0 = make_float2(0.f, 0.f), a1 = make_float2(0.f, 0.f);
    #pragma unroll 2
    for (int k = 0; k < 256; k += 4) {
      float2 w0 = *(const float2*)(W1 + (size_t)k * 512 + 2 * t);
      float2 w1 = *(const float2*)(W1 + (size_t)(k + 1) * 512 + 2 * t);
      float2 w2v = *(const float2*)(W1 + (size_t)(k + 2) * 512 + 2 * t);
      float2 w3v = *(const float2*)(W1 + (size_t)(k + 3) * 512 + 2 * t);
      float h00 = hs[0][k], h01 = hs[0][k + 1], h02 = hs[0][k + 2], h03 = hs[0][k + 3];
      float h10 = hs[1][k], h11 = hs[1][k + 1], h12 = hs[1][k + 2], h13 = hs[1][k + 3];
      a0.x = fmaf(h00, w0.x, a0.x); a0.y = fmaf(h00, w0.y, a0.y);
      a1.x = fmaf(h10, w0.x, a1.x); a1.y = fmaf(h10, w0.y, a1.y);
      a0.x = fmaf(h01, w1.x, a0.x); a0.y = fmaf(h01, w1.y, a0.y);
      a1.x = fmaf(h11, w1.x, a1.x); a1.y = fmaf(h11, w1.y, a1.y);
      a0.x = fmaf(h02, w2v.x, a0.x); a0.y = fmaf(h02, w2v.y, a0.y);
      a1.x = fmaf(h12, w2v.x, a1.x); a1.y = fmaf(h12, w2v.y, a1.y);
      a0.x = fmaf(h03, w3v.x, a0.x); a0.y = fmaf(h03, w3v.y, a0.y);
      a1.x = fmaf(h13, w3v.x, a1.x); a1.y = fmaf(h13, w3v.y, a1.y);
    }
    float2 bv = *(const float2*)(b1 + 2 * t);
    *(ushort2*)(hpb + (size_t)r0 * 512 + 2 * t) = pk_bf16(a0.x + bv.x, a0.y + bv.y);
    *(ushort2*)(hpb + (size_t)(r0 + 1) * 512 + 2 * t) = pk_bf16(a1.x + bv.x, a1.y + bv.y);
  } else if (b < 288) {               // ---- ep part: 8 rows, bf16 out
    const int r0 = (b - 256) * 8;
    sm[t] = e_feat[(size_t)r0 * 64 + t];
    sm[256 + t] = e_feat[(size_t)r0 * 64 + 256 + t];
    __syncthreads();
    float2 acc[8];
    #pragma unroll
    for (int i = 0; i < 8; ++i) acc[i] = make_float2(0.f, 0.f);
    for (int k = 0; k < 64; ++k) {
      float2 wv = *(const float2*)(W1 + (size_t)(256 + k) * 512 + 2 * t);
      #pragma unroll
      for (int i = 0; i < 8; ++i) {
        acc[i].x = fmaf(sm[i * 64 + k], wv.x, acc[i].x);
        acc[i].y = fmaf(sm[i * 64 + k], wv.y, acc[i].y);
      }
    }
    #pragma unroll
    for (int i = 0; i < 8; ++i)
      *(ushort2*)(epb + (size_t)(r0 + i) * 512 + 2 * t) = pk_bf16(acc[i].x, acc[i].y);
  } else {                            // ---- w2f pack
    const int bb = b - 288;           // 0..63
    const int k0 = (bb >> 3) * 64;
    const int c0 = (bb & 7) * 64;
    #pragma unroll
    for (int rr = 0; rr < 4; ++rr) {
      const int row = rr * 16 + (t >> 4);
      float4 v = *(const float4*)(W2 + (size_t)(k0 + row) * 512 + c0 + (t & 15) * 4);
      *(float4*)(&sm[row * 68 + (t & 15) * 4]) = v;
    }
    __syncthreads();
    #pragma unroll
    for (int s2 = 0; s2 < 2; ++s2) {
      const int s = t * 2 + s2;       // 0..511 (8 records x 64 lanes)
      const int rec = s >> 6, l = s & 63;
      const int jg = (c0 >> 4) + (rec & 3);
      const int ksg = (k0 >> 5) + (rec >> 2);
      const int cl = (rec & 3) * 16 + (l & 15);
      const int kl = (rec >> 2) * 32 + (l >> 4) * 8;
      union { ushort2 o[4]; uint4 v; } u;
      #pragma unroll
      for (int uu = 0; uu < 4; ++uu)
        u.o[uu] = pk_bf16(sm[(kl + 2 * uu) * 68 + cl], sm[(kl + 2 * uu + 1) * 68 + cl]);
      *(uint4*)(w2f + ((size_t)(jg * 16 + ksg) * 64 + l) * 8) = u.v;
    }
  }
}

// ---------------- main fused kernel ----------------
// 2048 blocks x 256 thr. Block = 64 rows (one bn, e-quarter) x all 512 cols.
// Wave w: cols w*128..+128 (j=0..7), rows 0..63 (i=0..3).
// Depth-2 B prefetch ping-pong; per-block K stagger spreads L2 traffic.
__global__ __launch_bounds__(256, 2) void k_main(
    const unsigned short* __restrict__ hpb, const unsigned short* __restrict__ epb,
    const unsigned short* __restrict__ w2f, const float* __restrict__ b2,
    const float* __restrict__ W3, const float* __restrict__ b3,
    float* __restrict__ out) {
  __shared__ unsigned short x1s[64 * 512];   // 64 KiB, XOR-swizzled 16B chunks

  const int t = threadIdx.x;
  const int lane = t & 63;
  const int w = t >> 6;          // 0..3 -> col group (128 cols)
  const int l15 = lane & 15, l4 = lane >> 4;
  const int bn = blockIdx.x >> 2;
  const int e0 = (blockIdx.x & 3) << 6;
  const int off = (blockIdx.x * 11) & 15;   // K stagger
  const unsigned short* hprow = hpb + (size_t)bn * 512;

  // b-frag ping-pong; preload ks-slot 0 and 1 (in flight across staging)
  const unsigned short* wrec = w2f + (size_t)w * 65536 + (size_t)lane * 8;
  bf16x8 bb[2][8];
  #pragma unroll
  for (int j = 0; j < 8; ++j) {
    bb[0][j] = *(const bf16x8*)(wrec + j * 8192 + (size_t)off * 512);
    bb[1][j] = *(const bf16x8*)(wrec + j * 8192 + (size_t)((off + 1) & 15) * 512);
  }

  // ---- stage x1 once: relu(hp + ep) -> bf16, chunk' = chunk ^ (row&7)
  {
    const int kk = t & 63;          // 16B-chunk index (8 bf16)
    const int rbase = t >> 6;       // 0..3
    union { uint4 v; unsigned short s[8]; } hv, ev, ov;
    hv.v = *(const uint4*)(hprow + kk * 8);
    float hf[8];
    #pragma unroll
    for (int u = 0; u < 8; ++u) hf[u] = bf2f(hv.s[u]);
    #pragma unroll 2
    for (int rr = 0; rr < 16; ++rr) {
      const int r = rr * 4 + rbase;
      ev.v = *(const uint4*)(epb + (size_t)(e0 + r) * 512 + kk * 8);
      #pragma unroll
      for (int u = 0; u < 4; ++u) {
        ushort2 p = pk_bf16(fmaxf(bf2f(ev.s[2 * u]) + hf[2 * u], 0.f),
                            fmaxf(bf2f(ev.s[2 * u + 1]) + hf[2 * u + 1], 0.f));
        ov.s[2 * u] = p.x;
        ov.s[2 * u + 1] = p.y;
      }
      *(uint4*)(&x1s[r * 512 + (kk ^ (r & 7)) * 8]) = ov.v;
    }
  }
  __syncthreads();

  f32x4 acc[4][8] = {};
  #pragma unroll 4
  for (int ks = 0; ks < 16; ++ks) {
    const int cur = ks & 1;
    const int kr = (ks + off) & 15;        // this iter's k-slot
    const int kr2 = (ks + 2 + off) & 15;   // prefetch slot (wraps: dummy reload)
    bf16x8 a[4];
    #pragma unroll
    for (int i = 0; i < 4; ++i) {
      const int r = i * 16 + l15;          // r&7 == l15&7
      a[i] = *(const bf16x8*)(&x1s[r * 512 + (((kr * 4 + l4) ^ (l15 & 7)) * 8)]);
    }
    #pragma unroll
    for (int i = 0; i < 4; ++i)
      #pragma unroll
      for (int j = 0; j < 8; ++j)
        acc[i][j] = __builtin_amdgcn_mfma_f32_16x16x32_bf16(a[i], bb[cur][j], acc[i][j], 0, 0, 0);
    #pragma unroll
    for (int j = 0; j < 8; ++j)
      bb[cur][j] = *(const bf16x8*)(wrec + j * 8192 + (size_t)kr2 * 512);
  }

  // ---- fused epilogue: osum[row] = sum_n relu(acc + b2[n]) * W3[n]
  float part[16];
  #pragma unroll
  for (int u = 0; u < 16; ++u) part[u] = 0.f;
  #pragma unroll
  for (int j = 0; j < 8; ++j) {
    const int n = w * 128 + j * 16 + l15;
    const float b2v = b2[n], w3v = W3[n];
    #pragma unroll
    for (int i = 0; i < 4; ++i)
      #pragma unroll
      for (int r = 0; r < 4; ++r)
        part[i * 4 + r] = fmaf(fmaxf(acc[i][j][r] + b2v, 0.f), w3v, part[i * 4 + r]);
  }
  #pragma unroll
  for (int u = 0; u < 16; ++u) {     // reduce over the 16 col-lanes (l15)
    float v = part[u];
    v += __shfl_xor(v, 1);
    v += __shfl_xor(v, 2);
    v += __shfl_xor(v, 4);
    v += __shfl_xor(v, 8);
    part[u] = v;
  }
  __syncthreads();                   // all x1s reads done before aliasing
  float* osum = (float*)x1s;         // [4 col-groups][64 rows]
  if (l15 == 0) {
    #pragma unroll
    for (int i = 0; i < 4; ++i)
      #pragma unroll
      for (int r = 0; r < 4; ++r)
        osum[w * 64 + i * 16 + l4 * 4 + r] = part[i * 4 + r];
  }
  __syncthreads();
  if (t < 64) {
    float s = b3[0] + osum[t] + osum[64 + t] + osum[128 + t] + osum[192 + t];
    out[(size_t)bn * 256 + e0 + t] = s;
  }
}

extern "C" void kernel_launch(void* const* d_in, const int* in_sizes, int n_in,
                              void* d_out, int out_size, void* d_ws, size_t ws_size,
                              hipStream_t stream) {
  const float* h_all  = (const float*)d_in[0];   // (8,64,256)
  const float* e_feat = (const float*)d_in[1];   // (256,64)
  const float* W1     = (const float*)d_in[2];   // (320,512)
  const float* b1     = (const float*)d_in[3];   // (512,)
  const float* W2     = (const float*)d_in[4];   // (512,512)
  const float* b2     = (const float*)d_in[5];   // (512,)
  const float* W3     = (const float*)d_in[6];   // (512,1)
  const float* b3     = (const float*)d_in[7];   // (1,)
  float* out = (float*)d_out;                    // 131072 f32

  // workspace: hpb 512KB bf16 | epb 256KB bf16 | w2f 512KB bf16
  unsigned short* hpb = (unsigned short*)d_ws;
  unsigned short* epb = hpb + 512 * 512;
  unsigned short* w2f = epb + 256 * 512;

  hipLaunchKernelGGL(k_prep, dim3(352), dim3(256), 0, stream,
                     h_all, e_feat, W1, b1, W2, hpb, epb, w2f);
  hipLaunchKernelGGL(k_main, dim3(2048), dim3(256), 0, stream,
                     hpb, epb, w2f, b2, W3, b3, out);
}